// Round 18
// baseline (128.465 us; speedup 1.0000x reference)
//
// MPModule fused pipeline, round 17 (identical to round 16 experiment).
// GEMM tiles widened 64x64 -> 128x64 (wave = 32 rows x 64 cols, acc[2][4]):
// per K=32 step 6 ds_read_b128 feed 8 MFMA (was 5 reads per 4 MFMA).
// Structure: cvt_all -> e_gemm(z) -> atb -> reduce_g -> h_mfma -> out_gemm.
#include <hip/hip_runtime.h>

#define NE 8192
#define DD 256
#define NSPLIT 32

typedef __attribute__((ext_vector_type(8))) short short8;
typedef __attribute__((ext_vector_type(4))) short short4v;
typedef __attribute__((ext_vector_type(8))) __bf16 bf16x8;
typedef __attribute__((ext_vector_type(4))) float floatx4;

__device__ __forceinline__ unsigned short f2bf(float f) {
  union { float f; unsigned int i; } v; v.f = f;
  unsigned int r = v.i + 0x7fffu + ((v.i >> 16) & 1u);
  return (unsigned short)(r >> 16);
}

__device__ __forceinline__ floatx4 mfma_bf16(short8 a, short8 b, floatx4 c) {
  return __builtin_amdgcn_mfma_f32_16x16x32_bf16(
      __builtin_bit_cast(bf16x8, a), __builtin_bit_cast(bf16x8, b), c, 0, 0, 0);
}

// ---------------------------------------------------------------------------
// K0: conversions, x read ONCE. Blocks [0,512): one 64x64 x-tile -> xb
// (row-major bf16) AND xT (transposed bf16). [512,560): W1/W2/W3a transpose.
__device__ __forceinline__ void tcvt_tile(float* ls,
                                          const float* __restrict__ src, int C,
                                          unsigned short* __restrict__ dst, int R,
                                          int r0, int c0, int tid) {
  const int rr = tid >> 4, c4 = (tid & 15) * 4;
#pragma unroll
  for (int k = 0; k < 4; ++k)
    *(floatx4*)&ls[(rr + k * 16) * 68 + c4] =
        *(const floatx4*)&src[(size_t)(r0 + rr + k * 16) * C + c0 + c4];
  __syncthreads();
  const int cc = tid >> 2, rb = (tid & 3) * 16;
  short8 o0, o1;
#pragma unroll
  for (int i = 0; i < 8; ++i) {
    o0[i] = (short)f2bf(ls[(rb + i) * 68 + cc]);
    o1[i] = (short)f2bf(ls[(rb + 8 + i) * 68 + cc]);
  }
  unsigned short* dp = &dst[(size_t)(c0 + cc) * R + r0 + rb];
  *(short8*)dp = o0;
  *(short8*)(dp + 8) = o1;
}

__global__ void cvt_all(const float* __restrict__ x, unsigned short* __restrict__ xb,
                        unsigned short* __restrict__ xT,
                        const float* __restrict__ W1, unsigned short* __restrict__ W1t,
                        const float* __restrict__ W2, unsigned short* __restrict__ W2t,
                        const float* __restrict__ W3, unsigned short* __restrict__ W3t0) {
  __shared__ float ls[64 * 68];
  const int b = blockIdx.x, tid = threadIdx.x;
  if (b < 512) {
    const int r0 = (b >> 2) * 64, c0 = (b & 3) * 64;
    const int rr = tid >> 4, c4 = (tid & 15) * 4;
#pragma unroll
    for (int k = 0; k < 4; ++k) {
      floatx4 v = *(const floatx4*)&x[(size_t)(r0 + rr + k * 16) * DD + c0 + c4];
      *(floatx4*)&ls[(rr + k * 16) * 68 + c4] = v;
      short4v s;
#pragma unroll
      for (int c = 0; c < 4; ++c) s[c] = (short)f2bf(v[c]);
      *(short4v*)&xb[(size_t)(r0 + rr + k * 16) * DD + c0 + c4] = s;
    }
    __syncthreads();
    const int cc = tid >> 2, rb = (tid & 3) * 16;
    short8 o0, o1;
#pragma unroll
    for (int i = 0; i < 8; ++i) {
      o0[i] = (short)f2bf(ls[(rb + i) * 68 + cc]);
      o1[i] = (short)f2bf(ls[(rb + 8 + i) * 68 + cc]);
    }
    unsigned short* dp = &xT[(size_t)(c0 + cc) * NE + r0 + rb];
    *(short8*)dp = o0;
    *(short8*)(dp + 8) = o1;
  } else {
    int t = b - 512;
    const float* src = (t < 16) ? W1 : ((t < 32) ? W2 : W3);
    unsigned short* dst = (t < 16) ? W1t : ((t < 32) ? W2t : W3t0);
    t &= 15;
    tcvt_tile(ls, src, DD, dst, DD, (t >> 2) * 64, (t & 3) * 64, tid);
  }
}

// ---------------------------------------------------------------------------
// K1: e_z = relu(xb @ Wt_z^T + b_z), z = blockIdx.z. Tile 128x64, BK=64
// (4 rounds), reg-prefetch. grid (4,64,2)=512, LDS 27,648 B -> 2 blocks/CU.
__global__ __launch_bounds__(256, 2)
void e_gemm(const unsigned short* __restrict__ xb,
            const unsigned short* __restrict__ W1t, const float* __restrict__ b1,
            const unsigned short* __restrict__ W2t, const float* __restrict__ b2,
            unsigned short* __restrict__ e1, unsigned short* __restrict__ e2,
            unsigned short* __restrict__ e1T, unsigned short* __restrict__ e2T)
{
  __shared__ __align__(16) unsigned short smA[128 * 72];  // [row][k]
  __shared__ __align__(16) unsigned short smB[64 * 72];   // [n][k]
  const int T = threadIdx.x, lane = T & 63, wv = T >> 6;
  const int q = lane >> 4, r = lane & 15;
  const int col0 = blockIdx.x * 64, row0 = blockIdx.y * 128;
  const int z = blockIdx.z;
  const unsigned short* Wt = z ? W2t : W1t;
  const float* bi = z ? b2 : b1;
  unsigned short* eo = z ? e2 : e1;
  unsigned short* eoT = z ? e2T : e1T;

  floatx4 acc[2][4];
#pragma unroll
  for (int i = 0; i < 2; ++i)
#pragma unroll
    for (int j = 0; j < 4; ++j) acc[i][j] = (floatx4){0.f, 0.f, 0.f, 0.f};

  short8 pa[4], pb[2];
#pragma unroll
  for (int p = 0; p < 4; ++p) {
    const int id = p * 256 + T, rr = id >> 3, k8 = (id & 7) * 8;
    pa[p] = *(const short8*)&xb[(size_t)(row0 + rr) * DD + k8];
  }
#pragma unroll
  for (int p = 0; p < 2; ++p) {
    const int id = p * 256 + T, nn = id >> 3, k8 = (id & 7) * 8;
    pb[p] = *(const short8*)&Wt[(size_t)(col0 + nn) * DD + k8];
  }

  for (int kc = 0; kc < 256; kc += 64) {
#pragma unroll
    for (int p = 0; p < 4; ++p) {
      const int id = p * 256 + T, rr = id >> 3, k8 = (id & 7) * 8;
      *(short8*)&smA[rr * 72 + k8] = pa[p];
    }
#pragma unroll
    for (int p = 0; p < 2; ++p) {
      const int id = p * 256 + T, nn = id >> 3, k8 = (id & 7) * 8;
      *(short8*)&smB[nn * 72 + k8] = pb[p];
    }
    __syncthreads();
    if (kc + 64 < 256) {
#pragma unroll
      for (int p = 0; p < 4; ++p) {
        const int id = p * 256 + T, rr = id >> 3, k8 = (id & 7) * 8;
        pa[p] = *(const short8*)&xb[(size_t)(row0 + rr) * DD + kc + 64 + k8];
      }
#pragma unroll
      for (int p = 0; p < 2; ++p) {
        const int id = p * 256 + T, nn = id >> 3, k8 = (id & 7) * 8;
        pb[p] = *(const short8*)&Wt[(size_t)(col0 + nn) * DD + kc + 64 + k8];
      }
    }
#pragma unroll
    for (int ks = 0; ks < 2; ++ks) {
      short8 af[2], bf[4];
#pragma unroll
      for (int i = 0; i < 2; ++i)
        af[i] = *(const short8*)&smA[(wv * 32 + i * 16 + r) * 72 + ks * 32 + q * 8];
#pragma unroll
      for (int j = 0; j < 4; ++j)
        bf[j] = *(const short8*)&smB[(j * 16 + r) * 72 + ks * 32 + q * 8];
#pragma unroll
      for (int i = 0; i < 2; ++i)
#pragma unroll
        for (int j = 0; j < 4; ++j)
          acc[i][j] = mfma_bf16(af[i], bf[j], acc[i][j]);
    }
    __syncthreads();
  }

#pragma unroll
  for (int j = 0; j < 4; ++j) {
    const int col = col0 + j * 16 + r;
    const float bv = bi[col];
#pragma unroll
    for (int i = 0; i < 2; ++i) {
      const int rowb = row0 + wv * 32 + i * 16 + q * 4;
      short4v tv;
#pragma unroll
      for (int t = 0; t < 4; ++t) {
        unsigned short h = f2bf(fmaxf(acc[i][j][t] + bv, 0.0f));
        tv[t] = (short)h;
        eo[(size_t)(rowb + t) * DD + col] = h;
      }
      *(short4v*)&eoT[(size_t)col * NE + rowb] = tv;
    }
  }
}

// ---------------------------------------------------------------------------
// K2: split-K partials P[(z*32+y)][n][m] of G = eT x. Tile 128(m)x64(n),
// j-span 256 (4 rounds of 64), reg-prefetch. grid (8,32,2)=512 -> 2/CU.
__global__ __launch_bounds__(256, 2)
void atb(const unsigned short* __restrict__ e1T, const unsigned short* __restrict__ e2T,
         const unsigned short* __restrict__ xT, float* __restrict__ P_T)
{
  __shared__ __align__(16) unsigned short smA[128 * 72];  // [m][j]
  __shared__ __align__(16) unsigned short smB[64 * 72];   // [n][j]
  const int T = threadIdx.x, lane = T & 63, wv = T >> 6;
  const int q = lane >> 4, r = lane & 15;
  const int m0 = (blockIdx.x >> 2) * 128, n0 = (blockIdx.x & 3) * 64;
  const int y = blockIdx.y, z = blockIdx.z;
  const int j0 = y * (NE / NSPLIT);
  const unsigned short* E = z ? e2T : e1T;
  float* P = P_T + (size_t)(z * NSPLIT + y) * 65536;

  floatx4 acc[2][4];
#pragma unroll
  for (int i = 0; i < 2; ++i)
#pragma unroll
    for (int j = 0; j < 4; ++j) acc[i][j] = (floatx4){0.f, 0.f, 0.f, 0.f};

  short8 pa[4], pb[2];
#pragma unroll
  for (int p = 0; p < 4; ++p) {
    const int id = p * 256 + T, mm = id >> 3, j8 = (id & 7) * 8;
    pa[p] = *(const short8*)&E[(size_t)(m0 + mm) * NE + j0 + j8];
  }
#pragma unroll
  for (int p = 0; p < 2; ++p) {
    const int id = p * 256 + T, nn = id >> 3, j8 = (id & 7) * 8;
    pb[p] = *(const short8*)&xT[(size_t)(n0 + nn) * NE + j0 + j8];
  }

  for (int jc = 0; jc < NE / NSPLIT; jc += 64) {
#pragma unroll
    for (int p = 0; p < 4; ++p) {
      const int id = p * 256 + T, mm = id >> 3, j8 = (id & 7) * 8;
      *(short8*)&smA[mm * 72 + j8] = pa[p];
    }
#pragma unroll
    for (int p = 0; p < 2; ++p) {
      const int id = p * 256 + T, nn = id >> 3, j8 = (id & 7) * 8;
      *(short8*)&smB[nn * 72 + j8] = pb[p];
    }
    __syncthreads();
    if (jc + 64 < NE / NSPLIT) {
#pragma unroll
      for (int p = 0; p < 4; ++p) {
        const int id = p * 256 + T, mm = id >> 3, j8 = (id & 7) * 8;
        pa[p] = *(const short8*)&E[(size_t)(m0 + mm) * NE + j0 + jc + 64 + j8];
      }
#pragma unroll
      for (int p = 0; p < 2; ++p) {
        const int id = p * 256 + T, nn = id >> 3, j8 = (id & 7) * 8;
        pb[p] = *(const short8*)&xT[(size_t)(n0 + nn) * NE + j0 + jc + 64 + j8];
      }
    }
#pragma unroll
    for (int ks = 0; ks < 2; ++ks) {
      short8 af[2], bf[4];
#pragma unroll
      for (int i = 0; i < 2; ++i)
        af[i] = *(const short8*)&smA[(wv * 32 + i * 16 + r) * 72 + ks * 32 + q * 8];
#pragma unroll
      for (int j = 0; j < 4; ++j)
        bf[j] = *(const short8*)&smB[(j * 16 + r) * 72 + ks * 32 + q * 8];
#pragma unroll
      for (int i = 0; i < 2; ++i)
#pragma unroll
        for (int j = 0; j < 4; ++j)
          acc[i][j] = mfma_bf16(af[i], bf[j], acc[i][j]);
    }
    __syncthreads();
  }
#pragma unroll
  for (int i = 0; i < 2; ++i)
#pragma unroll
    for (int j = 0; j < 4; ++j) {
      const int n = n0 + j * 16 + r;
      const int m = m0 + wv * 32 + i * 16 + q * 4;
      *(floatx4*)&P[(size_t)n * DD + m] = acc[i][j];
    }
}

// ---------------------------------------------------------------------------
// K3: G_T[z][n][m] = sum over y of P. 16 MB coalesced, 128 blocks x 256 thr.
__global__ void reduce_g(const float* __restrict__ P_T, float* __restrict__ G_T) {
  int idx = blockIdx.x * 256 + threadIdx.x;
  int z = idx >> 14, off = idx & 16383;
  const floatx4* Pp = (const floatx4*)P_T;
  floatx4 s = (floatx4){0.f, 0.f, 0.f, 0.f};
#pragma unroll
  for (int y = 0; y < NSPLIT; ++y)
    s += Pp[(size_t)(z * NSPLIT + y) * 16384 + off];
  ((floatx4*)G_T)[idx] = s;
}

// ---------------------------------------------------------------------------
// K4: Ht_z = transpose of H_z, H_z = (G_z/256) @ W3seg_z. 64x64 tiles,
// grid (16,1,2) on L2-hot G_T and W3.
__global__ __launch_bounds__(256, 2)
void h_mfma(const float* __restrict__ G_T, const float* __restrict__ W3,
            unsigned short* __restrict__ H1t, unsigned short* __restrict__ H2t)
{
  __shared__ __align__(16) unsigned short smA[64 * 136];
  __shared__ __align__(16) unsigned short smB[64 * 136];
  const int T = threadIdx.x, lane = T & 63, wv = T >> 6;
  const int q = lane >> 4, r = lane & 15;
  const int z = blockIdx.z;
  const int me0 = (blockIdx.x >> 2) * 64, m30 = (blockIdx.x & 3) * 64;
  const float* G = G_T + (size_t)z * 65536;
  unsigned short* Ht = z ? H2t : H1t;
  const int woff = 256 + z * 256;

  floatx4 acc[4];
#pragma unroll
  for (int j = 0; j < 4; ++j) acc[j] = (floatx4){0.f, 0.f, 0.f, 0.f};

  for (int lc = 0; lc < 256; lc += 128) {
#pragma unroll
    for (int p = 0; p < 2; ++p) {
      const int id = p * 256 + T, lb = id >> 4, e4 = id & 15;
      floatx4 grow[4], wrow[4];
#pragma unroll
      for (int i = 0; i < 4; ++i) {
        grow[i] = *(const floatx4*)&G[(size_t)(lc + lb * 4 + i) * DD + me0 + e4 * 4];
        wrow[i] = *(const floatx4*)&W3[(size_t)(woff + lc + lb * 4 + i) * DD + m30 + e4 * 4];
      }
#pragma unroll
      for (int s4 = 0; s4 < 4; ++s4) {
        const int c = (s4 + e4) & 3;
        short4v ga = {(short)f2bf(grow[0][c] * 0.00390625f),
                      (short)f2bf(grow[1][c] * 0.00390625f),
                      (short)f2bf(grow[2][c] * 0.00390625f),
                      (short)f2bf(grow[3][c] * 0.00390625f)};
        short4v wa = {(short)f2bf(wrow[0][c]), (short)f2bf(wrow[1][c]),
                      (short)f2bf(wrow[2][c]), (short)f2bf(wrow[3][c])};
        *(short4v*)&smA[(e4 * 4 + c) * 136 + lb * 4] = ga;
        *(short4v*)&smB[(e4 * 4 + c) * 136 + lb * 4] = wa;
      }
    }
    __syncthreads();
#pragma unroll
    for (int ks = 0; ks < 4; ++ks) {
      short8 af = *(const short8*)&smA[(wv * 16 + r) * 136 + ks * 32 + q * 8];
#pragma unroll
      for (int j = 0; j < 4; ++j) {
        short8 bf = *(const short8*)&smB[(j * 16 + r) * 136 + ks * 32 + q * 8];
        acc[j] = mfma_bf16(af, bf, acc[j]);
      }
    }
    __syncthreads();
  }
#pragma unroll
  for (int j = 0; j < 4; ++j) {
    const int m3 = m30 + j * 16 + r;
    const int me = me0 + wv * 16 + q * 4;
    short4v v;
#pragma unroll
    for (int i = 0; i < 4; ++i) v[i] = (short)f2bf(acc[j][i]);
    *(short4v*)&Ht[(size_t)m3 * DD + me] = v;
  }
}

// ---------------------------------------------------------------------------
// K5: out = relu(xb*W3a + e1*H1 + e2*H2 + b3), fp32 out. Tile 128x64, BK=64,
// 3 segs x 4 rounds = 12 rounds, reg-prefetch. grid (4,64)=256.
__global__ __launch_bounds__(256, 2)
void out_gemm(const unsigned short* __restrict__ xb,
              const unsigned short* __restrict__ e1, const unsigned short* __restrict__ e2,
              const unsigned short* __restrict__ W3t0,
              const unsigned short* __restrict__ H1t, const unsigned short* __restrict__ H2t,
              const float* __restrict__ b3, float* __restrict__ out)
{
  __shared__ __align__(16) unsigned short smA[128 * 72];
  __shared__ __align__(16) unsigned short smB[64 * 72];
  const int T = threadIdx.x, lane = T & 63, wv = T >> 6;
  const int q = lane >> 4, r = lane & 15;
  const int col0 = blockIdx.x * 64, row0 = blockIdx.y * 128;

  const unsigned short* As[3] = {xb, e1, e2};
  const unsigned short* Bs[3] = {W3t0, H1t, H2t};

  floatx4 acc[2][4];
#pragma unroll
  for (int i = 0; i < 2; ++i)
#pragma unroll
    for (int j = 0; j < 4; ++j) acc[i][j] = (floatx4){0.f, 0.f, 0.f, 0.f};

  short8 pa[4], pb[2];
#pragma unroll
  for (int p = 0; p < 4; ++p) {
    const int id = p * 256 + T, rr = id >> 3, k8 = (id & 7) * 8;
    pa[p] = *(const short8*)&As[0][(size_t)(row0 + rr) * DD + k8];
  }
#pragma unroll
  for (int p = 0; p < 2; ++p) {
    const int id = p * 256 + T, nn = id >> 3, k8 = (id & 7) * 8;
    pb[p] = *(const short8*)&Bs[0][(size_t)(col0 + nn) * DD + k8];
  }

  for (int rd = 0; rd < 12; ++rd) {
#pragma unroll
    for (int p = 0; p < 4; ++p) {
      const int id = p * 256 + T, rr = id >> 3, k8 = (id & 7) * 8;
      *(short8*)&smA[rr * 72 + k8] = pa[p];
    }
#pragma unroll
    for (int p = 0; p < 2; ++p) {
      const int id = p * 256 + T, nn = id >> 3, k8 = (id & 7) * 8;
      *(short8*)&smB[nn * 72 + k8] = pb[p];
    }
    __syncthreads();
    if (rd + 1 < 12) {
      const int s = (rd + 1) >> 2, kc = ((rd + 1) & 3) * 64;
      const unsigned short* A = As[s];
      const unsigned short* B = Bs[s];
#pragma unroll
      for (int p = 0; p < 4; ++p) {
        const int id = p * 256 + T, rr = id >> 3, k8 = (id & 7) * 8;
        pa[p] = *(const short8*)&A[(size_t)(row0 + rr) * DD + kc + k8];
      }
#pragma unroll
      for (int p = 0; p < 2; ++p) {
        const int id = p * 256 + T, nn = id >> 3, k8 = (id & 7) * 8;
        pb[p] = *(const short8*)&B[(size_t)(col0 + nn) * DD + kc + k8];
      }
    }
#pragma unroll
    for (int ks = 0; ks < 2; ++ks) {
      short8 af[2], bf[4];
#pragma unroll
      for (int i = 0; i < 2; ++i)
        af[i] = *(const short8*)&smA[(wv * 32 + i * 16 + r) * 72 + ks * 32 + q * 8];
#pragma unroll
      for (int j = 0; j < 4; ++j)
        bf[j] = *(const short8*)&smB[(j * 16 + r) * 72 + ks * 32 + q * 8];
#pragma unroll
      for (int i = 0; i < 2; ++i)
#pragma unroll
        for (int j = 0; j < 4; ++j)
          acc[i][j] = mfma_bf16(af[i], bf[j], acc[i][j]);
    }
    __syncthreads();
  }
#pragma unroll
  for (int j = 0; j < 4; ++j) {
    const int col = col0 + j * 16 + r;
    const float bv = b3[col];
#pragma unroll
    for (int i = 0; i < 2; ++i) {
      const int rowb = row0 + wv * 32 + i * 16 + q * 4;
#pragma unroll
      for (int t = 0; t < 4; ++t)
        out[(size_t)(rowb + t) * DD + col] = fmaxf(acc[i][j][t] + bv, 0.0f);
    }
  }
}

// ---------------------------------------------------------------------------
extern "C" void kernel_launch(void* const* d_in, const int* in_sizes, int n_in,
                              void* d_out, int out_size, void* d_ws, size_t ws_size,
                              hipStream_t stream) {
  (void)in_sizes; (void)n_in; (void)out_size; (void)ws_size;
  const float* x  = (const float*)d_in[3];
  const float* W1 = (const float*)d_in[5];
  const float* b1 = (const float*)d_in[6];
  const float* W2 = (const float*)d_in[7];
  const float* b2 = (const float*)d_in[8];
  const float* W3 = (const float*)d_in[9];
  const float* b3 = (const float*)d_in[10];
  float* out = (float*)d_out;

  char* ws = (char*)d_ws;
  const size_t MB = 1u << 20;
  const size_t KB = 1u << 10;
  unsigned short* xb   = (unsigned short*)ws;                          // 4 MB
  unsigned short* xT   = (unsigned short*)(ws + 4 * MB);               // 4 MB
  unsigned short* e1   = (unsigned short*)(ws + 8 * MB);               // 4 MB
  unsigned short* e2   = (unsigned short*)(ws + 12 * MB);              // 4 MB
  unsigned short* e1T  = (unsigned short*)(ws + 16 * MB);              // 4 MB
  unsigned short* e2T  = (unsigned short*)(ws + 20 * MB);              // 4 MB
  unsigned short* W1t  = (unsigned short*)(ws + 24 * MB);              // 128 KB
  unsigned short* W2t  = (unsigned short*)(ws + 24 * MB + 128 * KB);   // 128 KB
  unsigned short* W3t0 = (unsigned short*)(ws + 24 * MB + 256 * KB);   // 128 KB
  unsigned short* H1t  = (unsigned short*)(ws + 24 * MB + 384 * KB);   // 128 KB
  unsigned short* H2t  = (unsigned short*)(ws + 24 * MB + 512 * KB);   // 128 KB
  float* G_T           = (float*)(ws + 24 * MB + 640 * KB);            // 512 KB
  float* P_T           = (float*)(ws + 25 * MB);                       // 16 MB

  cvt_all<<<560, 256, 0, stream>>>(x, xb, xT, W1, W1t, W2, W2t, W3, W3t0);
  e_gemm<<<dim3(4, 64, 2), 256, 0, stream>>>(xb, W1t, b1, W2t, b2, e1, e2, e1T, e2T);
  atb<<<dim3(8, NSPLIT, 2), 256, 0, stream>>>(e1T, e2T, xT, P_T);
  reduce_g<<<128, 256, 0, stream>>>(P_T, G_T);
  h_mfma<<<dim3(16, 1, 2), 256, 0, stream>>>(G_T, W3, H1t, H2t);
  out_gemm<<<dim3(4, 64), 256, 0, stream>>>(xb, e1, e2, W3t0, H1t, H2t, b3, out);
}